// Round 2
// baseline (162.856 us; speedup 1.0000x reference)
//
#include <hip/hip_runtime.h>
#include <hip/hip_bf16.h>
#include <math.h>

// Problem constants
#define BQ 128
#define PP 256
#define MQ 16
#define MP 32
#define DD 768
#define MROWS (BQ*MQ)   // 2048
#define NROWS (PP*MP)   // 8192

typedef float f32x4 __attribute__((ext_vector_type(4)));

// ---------- fp32 -> fp8 e4m3 + k-shuffle, both tensors, one launch ----------
// Within each 64-k block, 16B chunk c holds k-groups {c, c+4}. One
// ds_read_b128 feeds TWO 16x16x32 MFMAs (k and k+32). Unchanged.
#define NQG (MROWS*96)   // 196608 groups of 8
#define NPG (NROWS*96)   // 786432

__global__ void conv_fp8_both(const float4* __restrict__ q, const float4* __restrict__ p,
                              unsigned char* __restrict__ qb, unsigned char* __restrict__ pb) {
    int idx = blockIdx.x * blockDim.x + threadIdx.x;
    const float4* in; unsigned char* out; int i;
    if (idx < NQG) { in = q; out = qb; i = idx; }
    else           { in = p; out = pb; i = idx - NQG; }
    float4 x0 = in[2 * i];
    float4 x1 = in[2 * i + 1];
    int lo = 0, hi = 0;
    lo = __builtin_amdgcn_cvt_pk_fp8_f32(x0.x, x0.y, lo, false);
    lo = __builtin_amdgcn_cvt_pk_fp8_f32(x0.z, x0.w, lo, true);
    hi = __builtin_amdgcn_cvt_pk_fp8_f32(x1.x, x1.y, hi, false);
    hi = __builtin_amdgcn_cvt_pk_fp8_f32(x1.z, x1.w, hi, true);
    int row = i / 96;
    int g96 = i - row * 96;
    int blk = g96 >> 3, g = g96 & 7;
    int dstoff = (g < 4) ? (g * 16) : ((g - 4) * 16 + 8);
    *(uint2*)(out + (size_t)row * DD + blk * 64 + dstoff) = make_uint2((unsigned)lo, (unsigned)hi);
}

// ---------- DPP wave-64 f32 reduction (pure VALU) ----------
__device__ inline float dpp_reduce_f32(float x) {
    int m;
    m = __builtin_amdgcn_update_dpp(0, __float_as_int(x), 0x111, 0xF, 0xF, true); x += __int_as_float(m);
    m = __builtin_amdgcn_update_dpp(0, __float_as_int(x), 0x112, 0xF, 0xF, true); x += __int_as_float(m);
    m = __builtin_amdgcn_update_dpp(0, __float_as_int(x), 0x114, 0xF, 0xF, true); x += __int_as_float(m);
    m = __builtin_amdgcn_update_dpp(0, __float_as_int(x), 0x118, 0xF, 0xF, true); x += __int_as_float(m);
    m = __builtin_amdgcn_update_dpp(0, __float_as_int(x), 0x142, 0xA, 0xF, true); x += __int_as_float(m);
    m = __builtin_amdgcn_update_dpp(0, __float_as_int(x), 0x143, 0xC, 0xF, true); x += __int_as_float(m);
    return x;   // lane 63 = total
}

// ---------- fused fp8 GEMM (128x128, BK=64, dbuf) + register select ---------
// This round:
//  - 128x128 tile, BK=64, double-buffered LDS (32 KB): grid 1024 blocks =
//    exactly 4/CU, ALL co-resident (LDS allows 5, VGPR budget 128 allows 4).
//    Zero straggler tail. Each LDS byte now feeds 2x the MFMAs.
//  - 2-phase pipeline (T3 minimal): STAGE(t+1) issued BEFORE ds_read+MFMA of
//    tile t; ONE __syncthreads per tile. The vmcnt drain at the barrier is
//    ~a full tile body downstream of the load issue (was 0 instrs -> full
//    L2 latency exposed every iter in rounds 0-1).
//  - launch_bounds(256,4): 128-reg budget, no forced spills (round 1's
//    (256,8) forced 64 regs -> 10 MB of scratch spill traffic).
// Accumulation order per acc element is IDENTICAL to rounds 0-1.
#define BM 128
#define BN 128
#define BK 64
#define KIT (DD / BK)   // 12

__device__ inline void load16_to_lds(const unsigned char* g, unsigned char* l) {
    __builtin_amdgcn_global_load_lds(
        (const __attribute__((address_space(1))) unsigned int*)(g),
        (__attribute__((address_space(3))) unsigned int*)(l),
        16, 0, 0);
}

__device__ inline float softplus_f(float x) {
    return (x > 20.f) ? x : log1pf(expf(x));
}

__device__ inline long lo64(int4 v) {
    return (long)(((unsigned long)(unsigned)v.y << 32) | (unsigned)v.x);
}
__device__ inline long hi64(int4 v) {
    return (long)(((unsigned long)(unsigned)v.w << 32) | (unsigned)v.z);
}

__global__ __launch_bounds__(256, 4) void gemm_select(const unsigned char* __restrict__ A,
                                                      const unsigned char* __restrict__ B,
                                                      const int* __restrict__ qm,
                                                      const int* __restrict__ pm,
                                                      const float* __restrict__ araw,
                                                      const float* __restrict__ braw,
                                                      float* __restrict__ logits) {
    __shared__ __align__(16) unsigned char sA[2][BM * BK];   // 2 x 8 KB
    __shared__ __align__(16) unsigned char sB[2][BN * BK];   // 2 x 8 KB

    const int tid  = threadIdx.x;
    const int lane = tid & 63;
    const int wid  = tid >> 6;        // 4 waves, 2x2 over 128x128
    const int wr   = wid >> 1;
    const int wc   = wid & 1;
    const int tileM = blockIdx.y * BM;
    const int tileN = blockIdx.x * BN;
    const int bBase = blockIdx.y * 8;   // 8 q-indices per tile
    const int pBase = blockIdx.x * 4;   // 4 p-indices per tile

    // ---- per-wave mask words: 4 q-blocks (rows wr*64..), 2 p-blocks
    unsigned qw[4]; int nq[4];
    #pragma unroll
    for (int t = 0; t < 4; ++t) {
        bool v = (lane < MQ) && (qm[(bBase + wr * 4 + t) * MQ + lane] != 0);
        unsigned long long bal = __ballot(v);
        qw[t] = (unsigned)bal;
        nq[t] = __popcll(bal);
    }
    unsigned pw[2]; int np_[2];
    #pragma unroll
    for (int t = 0; t < 2; ++t) {
        bool v = (lane < MP) && (pm[(pBase + wc * 2 + t) * MP + lane] != 0);
        unsigned long long bal = __ballot(v);
        pw[t] = (unsigned)bal;
        np_[t] = __popcll(bal);
    }

    // ---- GEMM phase (fp8, BK=64, double-buffered)
    f32x4 acc[4][4];
    #pragma unroll
    for (int i = 0; i < 4; ++i)
        #pragma unroll
        for (int j = 0; j < 4; ++j) {
            f32x4 z = {0.f, 0.f, 0.f, 0.f};
            acc[i][j] = z;
        }

    // staging: 4 x 16B per thread per iter (A pass0/pass1, B pass0/pass1).
    // 4 lanes per 64B row; global chunk fetched = l2 ^ sigma(row), LDS linear,
    // so LDS slot s holds logical chunk s ^ sigma(row) (involution).
    const int lr = lane >> 2, l2 = lane & 3;
    const int sg = (lane >> 3) & 3;                  // sigma(row): row%16 = lr
    const int chunkoff = ((l2 ^ sg) << 4);
    const unsigned char* pa0 = A + (size_t)(tileM + wid * 16 + lr) * DD + chunkoff;
    const unsigned char* pa1 = pa0 + (size_t)64 * DD;
    const unsigned char* pb0 = B + (size_t)(tileN + wid * 16 + lr) * DD + chunkoff;
    const unsigned char* pb1 = pb0 + (size_t)64 * DD;
    const int d0 = wid * 16 * BK;          // wave-uniform LDS byte offsets
    const int d1 = (64 + wid * 16) * BK;

    // read side: logical chunk q of row r lives at slot q ^ ((r>>1)&3)
    const int r0 = lane & 15;
    const int q  = lane >> 4;
    const int slotq = ((q ^ ((r0 >> 1) & 3)) << 4);
    int aoff[4], boff[4];
    #pragma unroll
    for (int mi = 0; mi < 4; ++mi)
        aoff[mi] = (wr * 64 + mi * 16 + r0) * BK + slotq;
    #pragma unroll
    for (int ni = 0; ni < 4; ++ni)
        boff[ni] = (wc * 64 + ni * 16 + r0) * BK + slotq;

    // prologue: stage tile 0 into buf 0
    load16_to_lds(pa0, &sA[0][d0]);
    load16_to_lds(pa1, &sA[0][d1]);
    load16_to_lds(pb0, &sB[0][d0]);
    load16_to_lds(pb1, &sB[0][d1]);
    pa0 += BK; pa1 += BK; pb0 += BK; pb1 += BK;
    __syncthreads();

    int cur = 0;
    for (int it = 0; it < KIT; ++it) {
        // issue next-tile stage FIRST: its latency hides under ds_read+MFMA
        if (it + 1 < KIT) {
            int nxt = cur ^ 1;
            load16_to_lds(pa0, &sA[nxt][d0]);
            load16_to_lds(pa1, &sA[nxt][d1]);
            load16_to_lds(pb0, &sB[nxt][d0]);
            load16_to_lds(pb1, &sB[nxt][d1]);
            pa0 += BK; pa1 += BK; pb0 += BK; pb1 += BK;
        }

        int4 afp[4], bfp[4];
        #pragma unroll
        for (int mi = 0; mi < 4; ++mi)
            afp[mi] = *(const int4*)(&sA[cur][aoff[mi]]);
        #pragma unroll
        for (int ni = 0; ni < 4; ++ni)
            bfp[ni] = *(const int4*)(&sB[cur][boff[ni]]);

        #pragma unroll
        for (int mi = 0; mi < 4; ++mi)
            #pragma unroll
            for (int ni = 0; ni < 4; ++ni)
                acc[mi][ni] = __builtin_amdgcn_mfma_f32_16x16x32_fp8_fp8(lo64(afp[mi]), lo64(bfp[ni]), acc[mi][ni], 0, 0, 0);
        #pragma unroll
        for (int mi = 0; mi < 4; ++mi)
            #pragma unroll
            for (int ni = 0; ni < 4; ++ni)
                acc[mi][ni] = __builtin_amdgcn_mfma_f32_16x16x32_fp8_fp8(hi64(afp[mi]), hi64(bfp[ni]), acc[mi][ni], 0, 0, 0);

        __syncthreads();   // drains stage (issued a full body ago) + flips
        cur ^= 1;
    }

    // ---- selection: 8 pairs/wave, 10-bit fixed-point keys, ballot counting
    // C/D layout (m89): row=(lane>>4)*4+(t&3), col=(t>>2)*16+(lane&15)
    float aco = softplus_f(araw[0]);
    float bco = softplus_f(braw[0]);
    const int rowb = (lane >> 4) * 4;
    const int colb = lane & 15;

    #pragma unroll 1
    for (int pair = 0; pair < 8; ++pair) {
        f32x4 w0, w1; unsigned qwv, pwv; int nqv, npv;
        switch (pair) {   // static acc indexing (rule #20: no runtime index)
        case 0:  w0 = acc[0][0]; w1 = acc[0][1]; qwv = qw[0]; nqv = nq[0]; pwv = pw[0]; npv = np_[0]; break;
        case 1:  w0 = acc[0][2]; w1 = acc[0][3]; qwv = qw[0]; nqv = nq[0]; pwv = pw[1]; npv = np_[1]; break;
        case 2:  w0 = acc[1][0]; w1 = acc[1][1]; qwv = qw[1]; nqv = nq[1]; pwv = pw[0]; npv = np_[0]; break;
        case 3:  w0 = acc[1][2]; w1 = acc[1][3]; qwv = qw[1]; nqv = nq[1]; pwv = pw[1]; npv = np_[1]; break;
        case 4:  w0 = acc[2][0]; w1 = acc[2][1]; qwv = qw[2]; nqv = nq[2]; pwv = pw[0]; npv = np_[0]; break;
        case 5:  w0 = acc[2][2]; w1 = acc[2][3]; qwv = qw[2]; nqv = nq[2]; pwv = pw[1]; npv = np_[1]; break;
        case 6:  w0 = acc[3][0]; w1 = acc[3][1]; qwv = qw[3]; nqv = nq[3]; pwv = pw[0]; npv = np_[0]; break;
        default: w0 = acc[3][2]; w1 = acc[3][3]; qwv = qw[3]; nqv = nq[3]; pwv = pw[1]; npv = np_[1]; break;
        }

        int n  = nqv * npv;               // >= 1
        int k  = (4 * n) / 10; if (k < 1) k = 1;
        int m2 = n - (8 * n) / 10;        // complement rank, >= 1

        float v[8] = {w0[0], w0[1], w0[2], w0[3], w1[0], w1[1], w1[2], w1[3]};
        int key[8];
        float tot = 0.f;
        #pragma unroll
        for (int t = 0; t < 8; ++t) {
            int row = rowb + (t & 3);
            int col = (t >> 2) * 16 + colb;
            int kf = (int)floorf(v[t] * 2.0f) + 512;     // monotone, |v| << 256
            kf = min(max(kf, 1), 1023);                  // v_med3_i32
            bool val = (((qwv >> row) & 1u) != 0u) && (((pwv >> col) & 1u) != 0u);
            key[t] = val ? kf : 0;                       // valid >= 1
            if (val) tot += v[t];
        }

        // dual 10-bit MSB-first radix descent: ballot -> s_bcnt1_b64 on the
        // scalar pipe; thresholds stay wave-uniform, no DPP, no readlane.
        int T1 = 0, T2 = 0;
        for (int bit = 9; bit >= 0; --bit) {
            int c1 = T1 | (1 << bit);
            int c2 = T2 | (1 << bit);
            int cnt1 = 0, cnt2 = 0;
            #pragma unroll
            for (int t = 0; t < 8; ++t) {
                cnt1 += __popcll(__ballot(key[t] >= c1));
                cnt2 += __popcll(__ballot(key[t] >= c2));
            }
            if (cnt1 >= k)  T1 = c1;
            if (cnt2 >= m2) T2 = c2;
        }

        // tie-corrected sums: f32 via DPP (lane 63), counts via ballot (uniform)
        float S1 = 0.f, S2 = 0.f;
        int c1n = 0, c2n = 0;
        #pragma unroll
        for (int t = 0; t < 8; ++t) {
            bool g1 = key[t] > T1;
            bool g2 = key[t] > T2;
            if (g1) S1 += v[t];
            if (g2) S2 += v[t];
            c1n += __popcll(__ballot(g1));
            c2n += __popcll(__ballot(g2));
        }
        S1  = dpp_reduce_f32(S1);
        S2  = dpp_reduce_f32(S2);
        tot = dpp_reduce_f32(tot);

        if (lane == 63) {
            float f1 = 0.5f * (float)(T1 - 512);   // tie-bucket lower edge
            float f2 = 0.5f * (float)(T2 - 512);
            float top = S1 + (float)(k  - c1n) * f1;
            float cmp = S2 + (float)(m2 - c2n) * f2;
            float bot = tot - cmp;
            int qi = pair >> 1, pi = pair & 1;
            logits[(bBase + wr * 4 + qi) * PP + (pBase + wc * 2 + pi)] = aco * top - bco * bot;
        }
    }
}

// ---------- loss = mean_b (lse(logits[b,:]) - logits[b,b]) ----------
__global__ __launch_bounds__(256) void loss_kernel(const float* __restrict__ logits,
                                                   float* __restrict__ loss_out) {
    __shared__ float warr[4];
    const int lane = threadIdx.x & 63;
    const int wid  = threadIdx.x >> 6;
    float acc = 0.f;
    for (int r = wid; r < BQ; r += 4) {
        const float* row = logits + r * PP;
        float x0 = row[lane], x1 = row[lane + 64], x2 = row[lane + 128], x3 = row[lane + 192];
        float m = fmaxf(fmaxf(x0, x1), fmaxf(x2, x3));
        #pragma unroll
        for (int off = 32; off > 0; off >>= 1)
            m = fmaxf(m, __shfl_xor(m, off, 64));
        float s = expf(x0 - m) + expf(x1 - m) + expf(x2 - m) + expf(x3 - m);
        #pragma unroll
        for (int off = 32; off > 0; off >>= 1)
            s += __shfl_xor(s, off, 64);
        float lse = m + logf(s);
        float diag = row[r];
        acc += (lse - diag);
    }
    if (lane == 0) warr[wid] = acc;
    __syncthreads();
    if (threadIdx.x == 0)
        loss_out[0] = (warr[0] + warr[1] + warr[2] + warr[3]) / (float)BQ;
}

extern "C" void kernel_launch(void* const* d_in, const int* in_sizes, int n_in,
                              void* d_out, int out_size, void* d_ws, size_t ws_size,
                              hipStream_t stream) {
    const float* q  = (const float*)d_in[0];
    const float* pe = (const float*)d_in[1];
    const int*   qm = (const int*)d_in[2];
    const int*   pm = (const int*)d_in[3];
    const float* ar = (const float*)d_in[4];
    const float* br = (const float*)d_in[5];
    float* out = (float*)d_out;           // [0] = loss, [1..32768] = logits

    // workspace: qb (1.5 MB fp8, k-shuffled) | pb (6 MB fp8, k-shuffled)
    char* ws = (char*)d_ws;
    unsigned char* qb = (unsigned char*)ws;
    unsigned char* pb = (unsigned char*)(ws + (size_t)MROWS * DD);

    // 1) convert fp32 -> fp8 e4m3 with k-shuffle (single launch)
    conv_fp8_both<<<(NQG + NPG) / 256, 256, 0, stream>>>(
        (const float4*)q, (const float4*)pe, qb, pb);

    // 2) fused fp8 sim-GEMM + dual top-k -> logits
    // 32 KB LDS dbuf; grid 1024 = exactly 4 blocks/CU, all co-resident
    dim3 gg(NROWS / BN, MROWS / BM, 1);   // (64, 16) = 1024 blocks
    gemm_select<<<gg, 256, 0, stream>>>(qb, pb, qm, pm, ar, br, out + 1);

    // 3) loss
    loss_kernel<<<1, 256, 0, stream>>>(out + 1, out);
}

// Round 4
// 148.332 us; speedup vs baseline: 1.0979x; 1.0979x over previous
//
#include <hip/hip_runtime.h>
#include <hip/hip_bf16.h>
#include <math.h>

// Problem constants
#define BQ 128
#define PP 256
#define MQ 16
#define MP 32
#define DD 768
#define MROWS (BQ*MQ)   // 2048
#define NROWS (PP*MP)   // 8192

typedef float f32x4 __attribute__((ext_vector_type(4)));

// ---------- fp32 -> fp8 e4m3 + k-shuffle, both tensors, one launch ----------
// Within each 64-k block, 16B chunk c holds k-groups {c, c+4}. One
// ds_read_b128 feeds TWO 16x16x32 MFMAs (k and k+32). Also zero-inits
// loss_out[0] (stream-ordered before loss_kernel).
#define NQG (MROWS*96)   // 196608 groups of 8
#define NPG (NROWS*96)   // 786432

__global__ void conv_fp8_both(const float4* __restrict__ q, const float4* __restrict__ p,
                              unsigned char* __restrict__ qb, unsigned char* __restrict__ pb,
                              float* __restrict__ loss_out) {
    int idx = blockIdx.x * blockDim.x + threadIdx.x;
    if (idx == 0) loss_out[0] = 0.f;
    const float4* in; unsigned char* out; int i;
    if (idx < NQG) { in = q; out = qb; i = idx; }
    else           { in = p; out = pb; i = idx - NQG; }
    float4 x0 = in[2 * i];
    float4 x1 = in[2 * i + 1];
    int lo = 0, hi = 0;
    lo = __builtin_amdgcn_cvt_pk_fp8_f32(x0.x, x0.y, lo, false);
    lo = __builtin_amdgcn_cvt_pk_fp8_f32(x0.z, x0.w, lo, true);
    hi = __builtin_amdgcn_cvt_pk_fp8_f32(x1.x, x1.y, hi, false);
    hi = __builtin_amdgcn_cvt_pk_fp8_f32(x1.z, x1.w, hi, true);
    int row = i / 96;
    int g96 = i - row * 96;
    int blk = g96 >> 3, g = g96 & 7;
    int dstoff = (g < 4) ? (g * 16) : ((g - 4) * 16 + 8);
    *(uint2*)(out + (size_t)row * DD + blk * 64 + dstoff) = make_uint2((unsigned)lo, (unsigned)hi);
}

// ---------- DPP wave-64 f32 reduction (pure VALU) ----------
__device__ inline float dpp_reduce_f32(float x) {
    int m;
    m = __builtin_amdgcn_update_dpp(0, __float_as_int(x), 0x111, 0xF, 0xF, true); x += __int_as_float(m);
    m = __builtin_amdgcn_update_dpp(0, __float_as_int(x), 0x112, 0xF, 0xF, true); x += __int_as_float(m);
    m = __builtin_amdgcn_update_dpp(0, __float_as_int(x), 0x114, 0xF, 0xF, true); x += __int_as_float(m);
    m = __builtin_amdgcn_update_dpp(0, __float_as_int(x), 0x118, 0xF, 0xF, true); x += __int_as_float(m);
    m = __builtin_amdgcn_update_dpp(0, __float_as_int(x), 0x142, 0xA, 0xF, true); x += __int_as_float(m);
    m = __builtin_amdgcn_update_dpp(0, __float_as_int(x), 0x143, 0xC, 0xF, true); x += __int_as_float(m);
    return x;   // lane 63 = total
}

// ---------- fused fp8 GEMM (64x256, BK=64, dbuf, 8 waves) + select ----------
// R3 design, resubmitted after infra failure (no kernel error surfaced).
//  - 64x256 tile, 512 threads (8 waves 2x4), BK=64, double-buffered 40 KB LDS
//    -> grid 32x32 = 1024 blocks = EXACTLY 4/CU (LDS 160/40=4), uniform,
//    zero tail; 4 blk x 8 waves = 32 waves/CU = 100% occupancy cap.
//  - acc is 2x4 frags (32 VGPR); B-frags consumed just-in-time.
//  - R2's one-barrier dbuf loop: stage(t+1) issued before reads+MFMA of t;
//    the vmcnt drain at the barrier is absorbed by 8 waves/SIMD TLP.
//  - NEW vs R3: mask-word setup moved AFTER the K-loop (shorter loop-carried
//    liveness under the (512,8) 64-VGPR budget -> less spill).
// Accumulation order per acc element is IDENTICAL to rounds 0-2.
#define BM 64
#define BN 256
#define BK 64
#define KIT (DD / BK)   // 12

__device__ inline void load16_to_lds(const unsigned char* g, unsigned char* l) {
    __builtin_amdgcn_global_load_lds(
        (const __attribute__((address_space(1))) unsigned int*)(g),
        (__attribute__((address_space(3))) unsigned int*)(l),
        16, 0, 0);
}

__device__ inline float softplus_f(float x) {
    return (x > 20.f) ? x : log1pf(expf(x));
}

__device__ inline long lo64(int4 v) {
    return (long)(((unsigned long)(unsigned)v.y << 32) | (unsigned)v.x);
}
__device__ inline long hi64(int4 v) {
    return (long)(((unsigned long)(unsigned)v.w << 32) | (unsigned)v.z);
}

__global__ __launch_bounds__(512, 8) void gemm_select(const unsigned char* __restrict__ A,
                                                      const unsigned char* __restrict__ B,
                                                      const int* __restrict__ qm,
                                                      const int* __restrict__ pm,
                                                      const float* __restrict__ araw,
                                                      const float* __restrict__ braw,
                                                      float* __restrict__ logits) {
    __shared__ __align__(16) unsigned char sA[2][BM * BK];   // 2 x 4 KB
    __shared__ __align__(16) unsigned char sB[2][BN * BK];   // 2 x 16 KB

    const int tid  = threadIdx.x;
    const int lane = tid & 63;
    const int wid  = tid >> 6;        // 8 waves: 2 (rows) x 4 (cols)
    const int wr   = wid >> 2;        // 0..1 -> rows wr*32..+32
    const int wc   = wid & 3;         // 0..3 -> cols wc*64..+64
    const int tileM = blockIdx.y * BM;
    const int tileN = blockIdx.x * BN;
    const int bBase = blockIdx.y * 4;   // 4 q-groups per tile
    const int pBase = blockIdx.x * 8;   // 8 p-groups per tile

    // ---- GEMM phase (fp8, BK=64, double-buffered)
    f32x4 acc[2][4];
    #pragma unroll
    for (int i = 0; i < 2; ++i)
        #pragma unroll
        for (int j = 0; j < 4; ++j) {
            f32x4 z = {0.f, 0.f, 0.f, 0.f};
            acc[i][j] = z;
        }

    // staging: A tile 64x64B = 256 chunks -> threads 0..255, 1 each;
    //          B tile 256x64B = 1024 chunks -> all 512 threads, 2 each.
    // global chunk fetched = l2 ^ sigma(row), LDS linear (involution).
    const int srow = tid >> 2;                       // 0..127
    const int l2   = tid & 3;
    const int sg   = (tid >> 3) & 3;                 // sigma(row) = (row>>1)&3
    const int chunkoff = ((l2 ^ sg) << 4);
    // clamp A-row for tid>=256 (pointer never dereferenced, but keep in-range)
    const int arow = (srow < 64) ? srow : 63;
    const unsigned char* pa  = A + (size_t)(tileM + arow) * DD + chunkoff;
    const unsigned char* pb0 = B + (size_t)(tileN + srow) * DD + chunkoff;
    const unsigned char* pb1 = pb0 + (size_t)128 * DD;   // rows +128: same sigma
    const int dAoff  = wid * 16 * BK;                // wave-uniform LDS offsets
    const int dB1off = (128 + wid * 16) * BK;

    // read side: logical chunk q of row r lives at slot q ^ ((r>>1)&3)
    const int r0 = lane & 15;
    const int qq = lane >> 4;
    const int slotq = ((qq ^ ((r0 >> 1) & 3)) << 4);
    const int abase = (wr * 32 + r0) * BK + slotq;   // + mi*16*BK
    const int bbase = (wc * 64 + r0) * BK + slotq;   // + ni*16*BK

    // prologue: stage tile 0 into buf 0
    if (tid < 256) load16_to_lds(pa, &sA[0][dAoff]);
    load16_to_lds(pb0, &sB[0][dAoff]);
    load16_to_lds(pb1, &sB[0][dB1off]);
    pa += BK; pb0 += BK; pb1 += BK;
    __syncthreads();

    int cur = 0;
    for (int it = 0; it < KIT; ++it) {
        // issue next-tile stage FIRST: latency hides under ds_read+MFMA
        if (it + 1 < KIT) {
            int nxt = cur ^ 1;
            if (tid < 256) load16_to_lds(pa, &sA[nxt][dAoff]);
            load16_to_lds(pb0, &sB[nxt][dAoff]);
            load16_to_lds(pb1, &sB[nxt][dB1off]);
            pa += BK; pb0 += BK; pb1 += BK;
        }

        int4 a0 = *(const int4*)(&sA[cur][abase]);
        int4 a1 = *(const int4*)(&sA[cur][abase + 16 * BK]);
        #pragma unroll
        for (int ni = 0; ni < 4; ++ni) {
            int4 b = *(const int4*)(&sB[cur][bbase + ni * 16 * BK]);
            acc[0][ni] = __builtin_amdgcn_mfma_f32_16x16x32_fp8_fp8(lo64(a0), lo64(b), acc[0][ni], 0, 0, 0);
            acc[1][ni] = __builtin_amdgcn_mfma_f32_16x16x32_fp8_fp8(lo64(a1), lo64(b), acc[1][ni], 0, 0, 0);
            acc[0][ni] = __builtin_amdgcn_mfma_f32_16x16x32_fp8_fp8(hi64(a0), hi64(b), acc[0][ni], 0, 0, 0);
            acc[1][ni] = __builtin_amdgcn_mfma_f32_16x16x32_fp8_fp8(hi64(a1), hi64(b), acc[1][ni], 0, 0, 0);
        }

        __syncthreads();   // drains stage (issued a full body ago) + flips
        cur ^= 1;
    }

    // ---- per-wave mask words (after K-loop: not live across it)
    unsigned qw[2]; int nq[2];
    #pragma unroll
    for (int t = 0; t < 2; ++t) {
        bool v = (lane < MQ) && (qm[(bBase + wr * 2 + t) * MQ + lane] != 0);
        unsigned long long bal = __ballot(v);
        qw[t] = (unsigned)bal;
        nq[t] = __popcll(bal);
    }
    unsigned pw[2]; int np_[2];
    #pragma unroll
    for (int t = 0; t < 2; ++t) {
        bool v = (lane < MP) && (pm[(pBase + wc * 2 + t) * MP + lane] != 0);
        unsigned long long bal = __ballot(v);
        pw[t] = (unsigned)bal;
        np_[t] = __popcll(bal);
    }

    // ---- selection: 4 pairs/wave, 10-bit fixed-point keys, ballot counting
    // C/D layout (m89): row=(lane>>4)*4+(t&3), col=(t>>2)*16+(lane&15)
    float aco = softplus_f(araw[0]);
    float bco = softplus_f(braw[0]);
    const int rowb = (lane >> 4) * 4;
    const int colb = lane & 15;

    #pragma unroll 1
    for (int pair = 0; pair < 4; ++pair) {
        f32x4 w0, w1; unsigned qwv, pwv; int nqv, npv;
        switch (pair) {   // static acc indexing (rule #20: no runtime index)
        case 0:  w0 = acc[0][0]; w1 = acc[0][1]; qwv = qw[0]; nqv = nq[0]; pwv = pw[0]; npv = np_[0]; break;
        case 1:  w0 = acc[0][2]; w1 = acc[0][3]; qwv = qw[0]; nqv = nq[0]; pwv = pw[1]; npv = np_[1]; break;
        case 2:  w0 = acc[1][0]; w1 = acc[1][1]; qwv = qw[1]; nqv = nq[1]; pwv = pw[0]; npv = np_[0]; break;
        default: w0 = acc[1][2]; w1 = acc[1][3]; qwv = qw[1]; nqv = nq[1]; pwv = pw[1]; npv = np_[1]; break;
        }

        int n  = nqv * npv;               // >= 1
        int k  = (4 * n) / 10; if (k < 1) k = 1;
        int m2 = n - (8 * n) / 10;        // complement rank, >= 1

        float v[8] = {w0[0], w0[1], w0[2], w0[3], w1[0], w1[1], w1[2], w1[3]};
        int key[8];
        float tot = 0.f;
        #pragma unroll
        for (int t = 0; t < 8; ++t) {
            int row = rowb + (t & 3);
            int col = (t >> 2) * 16 + colb;
            int kf = (int)floorf(v[t] * 2.0f) + 512;     // monotone, |v| << 256
            kf = min(max(kf, 1), 1023);                  // v_med3_i32
            bool val = (((qwv >> row) & 1u) != 0u) && (((pwv >> col) & 1u) != 0u);
            key[t] = val ? kf : 0;                       // valid >= 1
            if (val) tot += v[t];
        }

        // dual 10-bit MSB-first radix descent: ballot -> s_bcnt1_b64 on the
        // scalar pipe; thresholds stay wave-uniform, no DPP, no readlane.
        int T1 = 0, T2 = 0;
        for (int bit = 9; bit >= 0; --bit) {
            int c1 = T1 | (1 << bit);
            int c2 = T2 | (1 << bit);
            int cnt1 = 0, cnt2 = 0;
            #pragma unroll
            for (int t = 0; t < 8; ++t) {
                cnt1 += __popcll(__ballot(key[t] >= c1));
                cnt2 += __popcll(__ballot(key[t] >= c2));
            }
            if (cnt1 >= k)  T1 = c1;
            if (cnt2 >= m2) T2 = c2;
        }

        // tie-corrected sums: f32 via DPP (lane 63), counts via ballot (uniform)
        float S1 = 0.f, S2 = 0.f;
        int c1n = 0, c2n = 0;
        #pragma unroll
        for (int t = 0; t < 8; ++t) {
            bool g1 = key[t] > T1;
            bool g2 = key[t] > T2;
            if (g1) S1 += v[t];
            if (g2) S2 += v[t];
            c1n += __popcll(__ballot(g1));
            c2n += __popcll(__ballot(g2));
        }
        S1  = dpp_reduce_f32(S1);
        S2  = dpp_reduce_f32(S2);
        tot = dpp_reduce_f32(tot);

        if (lane == 63) {
            float f1 = 0.5f * (float)(T1 - 512);   // tie-bucket lower edge
            float f2 = 0.5f * (float)(T2 - 512);
            float top = S1 + (float)(k  - c1n) * f1;
            float cmp = S2 + (float)(m2 - c2n) * f2;
            float bot = tot - cmp;
            int qi = pair >> 1, pi = pair & 1;
            logits[(bBase + wr * 2 + qi) * PP + (pBase + wc * 2 + pi)] = aco * top - bco * bot;
        }
    }
}

// ---------- loss = mean_b (lse(logits[b,:]) - logits[b,b]) ----------
// 32 blocks x 4 waves, one row per wave, atomicAdd partials (out[0] zeroed
// by conv_fp8_both, stream-ordered). Was a single serial block.
__global__ __launch_bounds__(256) void loss_kernel(const float* __restrict__ logits,
                                                   float* __restrict__ loss_out) {
    const int lane = threadIdx.x & 63;
    const int wid  = threadIdx.x >> 6;
    const int r = blockIdx.x * 4 + wid;
    const float* row = logits + r * PP;
    float x0 = row[lane], x1 = row[lane + 64], x2 = row[lane + 128], x3 = row[lane + 192];
    float m = fmaxf(fmaxf(x0, x1), fmaxf(x2, x3));
    #pragma unroll
    for (int off = 32; off > 0; off >>= 1)
        m = fmaxf(m, __shfl_xor(m, off, 64));
    float s = expf(x0 - m) + expf(x1 - m) + expf(x2 - m) + expf(x3 - m);
    #pragma unroll
    for (int off = 32; off > 0; off >>= 1)
        s += __shfl_xor(s, off, 64);
    if (lane == 0)
        atomicAdd(loss_out, (m + logf(s) - row[r]) * (1.0f / (float)BQ));
}

extern "C" void kernel_launch(void* const* d_in, const int* in_sizes, int n_in,
                              void* d_out, int out_size, void* d_ws, size_t ws_size,
                              hipStream_t stream) {
    const float* q  = (const float*)d_in[0];
    const float* pe = (const float*)d_in[1];
    const int*   qm = (const int*)d_in[2];
    const int*   pm = (const int*)d_in[3];
    const float* ar = (const float*)d_in[4];
    const float* br = (const float*)d_in[5];
    float* out = (float*)d_out;           // [0] = loss, [1..32768] = logits

    // workspace: qb (1.5 MB fp8, k-shuffled) | pb (6 MB fp8, k-shuffled)
    char* ws = (char*)d_ws;
    unsigned char* qb = (unsigned char*)ws;
    unsigned char* pb = (unsigned char*)(ws + (size_t)MROWS * DD);

    // 1) convert fp32 -> fp8 e4m3 with k-shuffle (+ zero loss accumulator)
    conv_fp8_both<<<(NQG + NPG) / 256, 256, 0, stream>>>(
        (const float4*)q, (const float4*)pe, qb, pb, out);

    // 2) fused fp8 sim-GEMM + dual top-k -> logits
    // 40 KB LDS dbuf; grid 1024 = exactly 4 blocks/CU = 32 waves/CU cap
    dim3 gg(NROWS / BN, MROWS / BM, 1);   // (32, 32) = 1024 blocks
    gemm_select<<<gg, 512, 0, stream>>>(qb, pb, qm, pm, ar, br, out + 1);

    // 3) loss (parallel, atomic accumulate)
    loss_kernel<<<32, 256, 0, stream>>>(out + 1, out);
}